// Round 9
// baseline (574.669 us; speedup 1.0000x reference)
//
#include <hip/hip_runtime.h>
#include <hip/hip_bf16.h>

typedef float f32x4 __attribute__((ext_vector_type(4)));
typedef __bf16 bf16x8 __attribute__((ext_vector_type(8)));
typedef unsigned short u16x4 __attribute__((ext_vector_type(4)));

__device__ __forceinline__ unsigned short f2bf(float f) {
  unsigned u = __builtin_bit_cast(unsigned, f);
  u += 0x7FFFu + ((u >> 16) & 1u);
  return (unsigned short)(u >> 16);
}
__device__ __forceinline__ float bf2f(unsigned short h) {
  unsigned u = ((unsigned)h) << 16;
  return __builtin_bit_cast(float, u);
}

__device__ __forceinline__ void gload_lds16(const void* g, void* l) {
  __builtin_amdgcn_global_load_lds(
      (const __attribute__((address_space(1))) void*)g,
      (__attribute__((address_space(3))) void*)l, 16, 0, 0);
}

// ------------- 256x256 2-phase-per-K-tile bf16 GEMM (round-8 schedule) ------
// C[m][n] = scale * sum_k A[m][k]*B[n][k] (+ bias[n]). A:[M][K], B:[N][K] bf16.
// Round-9 change here: s_setprio removed (8 lockstep waves = m190's regime
// where setprio measured mildly negative). Everything else identical to r8.
constexpr int BM = 256, BN = 256, BK = 64;

#define BAR() __builtin_amdgcn_s_barrier()
#define LGKM0()                                        \
  do {                                                 \
    asm volatile("s_waitcnt lgkmcnt(0)" ::: "memory"); \
    __builtin_amdgcn_sched_barrier(0);                 \
  } while (0)
#define VMW(N) asm volatile("s_waitcnt vmcnt(" #N ")" ::: "memory")

#define MM(a_, b_, c_)                                                        \
  c_ = __builtin_amdgcn_mfma_f32_16x16x32_bf16(                               \
      __builtin_bit_cast(bf16x8, a_), __builtin_bit_cast(bf16x8, b_), c_, 0, 0, 0)

template <int OUT_MODE, bool HAS_BIAS>
__global__ __launch_bounds__(512, 2) void gemm256(
    const unsigned short* __restrict__ A, const unsigned short* __restrict__ B,
    const float* __restrict__ bias, float scale, void* __restrict__ Cv,
    int N, int K, long sA, long sB, long sC, int gx, int gy) {
  __shared__ char sm[131072];  // A: [0,64K): dbuf*32K + half*16K; B: +64K same

  const int nwg = gridDim.x;
  int id = blockIdx.x;
  id = (id & 7) * (nwg >> 3) + (id >> 3);  // XCD swizzle (nwg % 8 == 0)
  const int bx = id % gx;
  const int by = (id / gx) % gy;
  const int bz = id / (gx * gy);

  const int t = threadIdx.x;
  const int lane = t & 63;
  const int w = t >> 6;   // 0..7
  const int wm = w >> 2;  // 0..1
  const int wn = w & 3;   // 0..3

  const int rowBase = by * BM;
  const int colBase = bx * BN;
  const unsigned short* Ab = A + sA * bz;
  const unsigned short* Bb = B + sB * bz;
  const int NT = K >> 6;  // K-tiles of 64 (even, >= 2)

  // staging: half-tile = 128 rows x 64 cols; wave w issue j covers rows
  // [(w+8j)*8,+8); lane l -> row +(l>>3), slot l&7; source chunk inverse-swz.
  const int srl = lane >> 3;
  const int schunk = (lane & 7) ^ srl;

#define STAGE_A(tt, h, d)                                                     \
  do {                                                                        \
    int _kt = (tt); if (_kt > NT - 1) _kt = NT - 1;                           \
    const int _k0 = _kt << 6;                                                 \
    _Pragma("unroll") for (int _j = 0; _j < 2; ++_j) {                        \
      const int _r = (w + 8 * _j) * 8 + srl;                                  \
      gload_lds16(Ab + (size_t)(rowBase + (h) * 128 + _r) * K + _k0 + schunk * 8, \
                  sm + (d) * 32768 + (h) * 16384 + (w + 8 * _j) * 1024);      \
    }                                                                         \
  } while (0)
#define STAGE_B(tt, h, d)                                                     \
  do {                                                                        \
    int _kt = (tt); if (_kt > NT - 1) _kt = NT - 1;                           \
    const int _k0 = _kt << 6;                                                 \
    _Pragma("unroll") for (int _j = 0; _j < 2; ++_j) {                        \
      const int _r = (w + 8 * _j) * 8 + srl;                                  \
      gload_lds16(Bb + (size_t)(colBase + (h) * 128 + _r) * K + _k0 + schunk * 8, \
                  sm + 65536 + (d) * 32768 + (h) * 16384 + (w + 8 * _j) * 1024); \
    }                                                                         \
  } while (0)

  // fragment reads (half-aligned): A row = mh*128 + wm*64 + f*16 + lr,
  // B col = nh*128 + wn*32 + f*16 + lr. byte = row*128 + (chunk^(row&7))*16;
  // row&7 == lr&7 (all other terms are multiples of 8+).
  const int lr = lane & 15;
  const int g0 = lane >> 4;
  const int sw0 = (g0 ^ (lr & 7)) << 4;
  const int sw1 = ((g0 + 4) ^ (lr & 7)) << 4;
  const int aBase = wm * 8192 + lr * 128;
  const int bBase = 65536 + wn * 4096 + lr * 128;

  uint4 Ar[4][2], Br0[2][2], Br1[2][2];
  f32x4 acc[8][4];
#pragma unroll
  for (int m = 0; m < 8; ++m)
#pragma unroll
    for (int n = 0; n < 4; ++n) acc[m][n] = (f32x4){0.f, 0.f, 0.f, 0.f};

#define READ_A(d, mh)                                                         \
  do {                                                                        \
    _Pragma("unroll") for (int f = 0; f < 4; ++f) {                           \
      Ar[f][0] = *(const uint4*)(sm + (d) * 32768 + (mh) * 16384 + aBase + f * 2048 + sw0); \
      Ar[f][1] = *(const uint4*)(sm + (d) * 32768 + (mh) * 16384 + aBase + f * 2048 + sw1); \
    }                                                                         \
  } while (0)
#define READ_B0(d)                                                            \
  do {                                                                        \
    _Pragma("unroll") for (int f = 0; f < 2; ++f) {                           \
      Br0[f][0] = *(const uint4*)(sm + (d) * 32768 + bBase + f * 2048 + sw0); \
      Br0[f][1] = *(const uint4*)(sm + (d) * 32768 + bBase + f * 2048 + sw1); \
    }                                                                         \
  } while (0)
#define READ_B1(d)                                                            \
  do {                                                                        \
    _Pragma("unroll") for (int f = 0; f < 2; ++f) {                           \
      Br1[f][0] = *(const uint4*)(sm + (d) * 32768 + 16384 + bBase + f * 2048 + sw0); \
      Br1[f][1] = *(const uint4*)(sm + (d) * 32768 + 16384 + bBase + f * 2048 + sw1); \
    }                                                                         \
  } while (0)

#define MFMA_Q(Bset, mh, nh)                                                  \
  do {                                                                        \
    _Pragma("unroll") for (int kk = 0; kk < 2; ++kk)                          \
        _Pragma("unroll") for (int mf = 0; mf < 4; ++mf)                      \
            _Pragma("unroll") for (int nf = 0; nf < 2; ++nf)                  \
                MM(Ar[mf][kk], Bset[nf][kk], acc[(mh) * 4 + mf][(nh) * 2 + nf]); \
  } while (0)

  // Two phases per K-tile; stages target regions >=1 barrier past their last
  // read (A-h1 of buf d^1 last read at ph-B of the previous tile; A-h0/B-h0/
  // B-h1 of buf d last read at ph-A of this tile).
#define TILE2(t_, d_)                                                         \
  do {                                                                        \
    /* ph-A */ READ_B0(d_); READ_B1(d_); READ_A(d_, 0);                       \
    STAGE_A((t_) + 1, 1, (d_) ^ 1);                                           \
    BAR();                                                                    \
    MFMA_Q(Br0, 0, 0); MFMA_Q(Br1, 0, 1);                                     \
    BAR();                                                                    \
    /* ph-B */ READ_A(d_, 1);                                                 \
    STAGE_A((t_) + 2, 0, d_); STAGE_B((t_) + 2, 0, d_); STAGE_B((t_) + 2, 1, d_); \
    BAR();                                                                    \
    MFMA_Q(Br1, 1, 1); MFMA_Q(Br0, 1, 0);                                     \
    VMW(6);                                                                   \
    BAR();                                                                    \
  } while (0)

  // prologue: t0 fully staged (8 loads/wave) + t1's A-h0,B-h0,B-h1 (6);
  // A-h1(t1) is staged at tile0 ph-A. VMW(6) = t0 landed, t1's 6 in flight.
  STAGE_A(0, 0, 0); STAGE_B(0, 0, 0); STAGE_B(0, 1, 0); STAGE_A(0, 1, 0);
  STAGE_A(1, 0, 1); STAGE_B(1, 0, 1); STAGE_B(1, 1, 1);
  VMW(6);
  BAR();

  for (int i = 0; i < (NT >> 1); ++i) {
    TILE2(2 * i, 0);
    TILE2(2 * i + 1, 1);
  }
  VMW(0);  // drain clamped tail prefetches before teardown

  // Epilogue. acc[m][n]: row = (m>>2)*128 + wm*64 + (m&3)*16 + g0*4 + r,
  //                      col = (n>>1)*128 + wn*32 + (n&1)*16 + lr.
#pragma unroll
  for (int n = 0; n < 4; ++n) {
    const int col = colBase + (n >> 1) * 128 + wn * 32 + (n & 1) * 16 + lr;
    float bvv = 0.f;
    if constexpr (HAS_BIAS) bvv = bias[col];
#pragma unroll
    for (int m = 0; m < 8; ++m) {
      const int row0 = rowBase + (m >> 2) * 128 + wm * 64 + (m & 3) * 16 + g0 * 4;
      f32x4 v = acc[m][n];
      if constexpr (OUT_MODE == 0) {
        unsigned short* C = (unsigned short*)Cv + sC * bz;
#pragma unroll
        for (int r = 0; r < 4; ++r)
          C[(size_t)(row0 + r) * N + col] = f2bf(v[r] * scale + bvv);
      } else if constexpr (OUT_MODE == 1) {
        unsigned short* C = (unsigned short*)Cv;
        const int b = row0 >> 11, s = row0 & 2047;
        u16x4 pk;
#pragma unroll
        for (int r = 0; r < 4; ++r) pk[r] = f2bf(v[r] * scale + bvv);
        *(u16x4*)&C[((size_t)b * N + col) * 2048 + s] = pk;
      } else {
        float* C = (float*)Cv + sC * bz;
#pragma unroll
        for (int r = 0; r < 4; ++r)
          C[(size_t)(row0 + r) * N + col] = v[r] * scale + bvv;
      }
    }
  }
}

// ---- Projection GEMM: A fp32 [M][K] reg-staged with fused fp32->bf16 ------
// C = A @ Bw^T + bias; Bw bf16 [N][K] (pre-converted W, gload_lds-staged).
// Eliminates the standalone embedding conversion pass. Ledger (tile t, buf
// d=t&1): phA reads all frags of d (drained by lgkmcnt(0) before BAR1, so
// phB's B(t+2)->d DMA can't race them); phB: CVT+ds_write A(t+1)->d^1 (A
// region of d^1 last read tile t-1; writes drained by lgkmcnt(0) before
// BAR2), reload A(t+2)->regs (full-tile latency cover). B(t+1) landing is
// implied by the compiler's vmcnt wait on A(t+1) regs (B(t+1) is older in
// the in-order vmcnt queue) -- no manual VMW needed in the loop.
template <int OUT_MODE>
__global__ __launch_bounds__(512, 2) void gemmP(
    const float* __restrict__ Ap, const unsigned short* __restrict__ Bw,
    const float* __restrict__ bias, void* __restrict__ Cv, int N, int K,
    int gx, int gy) {
  __shared__ char sm[131072];

  const int nwg = gridDim.x;
  int id = blockIdx.x;
  id = (id & 7) * (nwg >> 3) + (id >> 3);  // XCD swizzle
  const int bx = id % gx;
  const int by = (id / gx) % gy;

  const int t = threadIdx.x;
  const int lane = t & 63;
  const int w = t >> 6;
  const int wm = w >> 2;
  const int wn = w & 3;

  const int rowBase = by * BM;
  const int colBase = bx * BN;
  const unsigned short* Bb = Bw;  // STAGE_B macro expects Bb
  const int NT = K >> 6;

  const int srl = lane >> 3;
  const int schunk = (lane & 7) ^ srl;

  // A staging role: thread t covers row arow (both halves), 16-col slice cpair.
  const int arow = t >> 2;   // 0..127
  const int cpair = t & 3;   // cols [cpair*16, +16)

  const int lr = lane & 15;
  const int g0 = lane >> 4;
  const int sw0 = (g0 ^ (lr & 7)) << 4;
  const int sw1 = ((g0 + 4) ^ (lr & 7)) << 4;
  const int aBase = wm * 8192 + lr * 128;
  const int bBase = 65536 + wn * 4096 + lr * 128;

  uint4 Ar[4][2], Br0[2][2], Br1[2][2];
  float4 Areg[2][4];
  f32x4 acc[8][4];
#pragma unroll
  for (int m = 0; m < 8; ++m)
#pragma unroll
    for (int n = 0; n < 4; ++n) acc[m][n] = (f32x4){0.f, 0.f, 0.f, 0.f};

#define LOAD_AP(tt)                                                           \
  do {                                                                        \
    int _kt = (tt); if (_kt > NT - 1) _kt = NT - 1;                           \
    const float* _ap = Ap + (size_t)(rowBase + arow) * K + (_kt << 6) + cpair * 16; \
    _Pragma("unroll") for (int _h = 0; _h < 2; ++_h)                          \
      _Pragma("unroll") for (int _i = 0; _i < 4; ++_i)                        \
        Areg[_h][_i] = *(const float4*)(_ap + (size_t)_h * 128 * K + _i * 4); \
  } while (0)

#define CVTW_AP(d)                                                            \
  do {                                                                        \
    _Pragma("unroll") for (int _h = 0; _h < 2; ++_h) {                        \
      unsigned short _hh[16];                                                 \
      _Pragma("unroll") for (int _i = 0; _i < 4; ++_i) {                      \
        _hh[_i * 4 + 0] = f2bf(Areg[_h][_i].x);                               \
        _hh[_i * 4 + 1] = f2bf(Areg[_h][_i].y);                               \
        _hh[_i * 4 + 2] = f2bf(Areg[_h][_i].z);                               \
        _hh[_i * 4 + 3] = f2bf(Areg[_h][_i].w);                               \
      }                                                                       \
      char* _b = sm + (d) * 32768 + _h * 16384 + arow * 128;                  \
      *(uint4*)(_b + (((2 * cpair) ^ (arow & 7)) << 4)) = *(uint4*)&_hh[0];   \
      *(uint4*)(_b + (((2 * cpair + 1) ^ (arow & 7)) << 4)) = *(uint4*)&_hh[8]; \
    }                                                                         \
  } while (0)

#define TILE_P(t_, d_)                                                        \
  do {                                                                        \
    READ_B0(d_); READ_B1(d_); READ_A(d_, 0);                                  \
    LGKM0();                                                                  \
    BAR();                                                                    \
    STAGE_B((t_) + 2, 0, d_); STAGE_B((t_) + 2, 1, d_);                       \
    CVTW_AP((d_) ^ 1);                                                        \
    LOAD_AP((t_) + 2);                                                        \
    MFMA_Q(Br0, 0, 0); MFMA_Q(Br1, 0, 1);                                     \
    READ_A(d_, 1);                                                            \
    MFMA_Q(Br1, 1, 1); MFMA_Q(Br0, 1, 0);                                     \
    LGKM0();                                                                  \
    BAR();                                                                    \
  } while (0)

  // prologue: B(0)->buf0, A(0)->regs, B(1)->buf1, A(0)->buf0 (cvt implies
  // B(0) retired: older in queue), A(1)->regs; drain writes; barrier.
  STAGE_B(0, 0, 0); STAGE_B(0, 1, 0);
  LOAD_AP(0);
  STAGE_B(1, 0, 1); STAGE_B(1, 1, 1);
  CVTW_AP(0);
  LOAD_AP(1);
  LGKM0();
  BAR();

  for (int i = 0; i < (NT >> 1); ++i) {
    TILE_P(2 * i, 0);
    TILE_P(2 * i + 1, 1);
  }
  VMW(0);  // drain clamped tail prefetches before teardown

  // Epilogue (bias always, scale 1).
#pragma unroll
  for (int n = 0; n < 4; ++n) {
    const int col = colBase + (n >> 1) * 128 + wn * 32 + (n & 1) * 16 + lr;
    const float bvv = bias[col];
#pragma unroll
    for (int m = 0; m < 8; ++m) {
      const int row0 = rowBase + (m >> 2) * 128 + wm * 64 + (m & 3) * 16 + g0 * 4;
      f32x4 v = acc[m][n];
      if constexpr (OUT_MODE == 0) {
        unsigned short* C = (unsigned short*)Cv;
#pragma unroll
        for (int r = 0; r < 4; ++r)
          C[(size_t)(row0 + r) * N + col] = f2bf(v[r] + bvv);
      } else {
        unsigned short* C = (unsigned short*)Cv;
        const int b = row0 >> 11, s = row0 & 2047;
        u16x4 pk;
#pragma unroll
        for (int r = 0; r < 4; ++r) pk[r] = f2bf(v[r] + bvv);
        *(u16x4*)&C[((size_t)b * N + col) * 2048 + s] = pk;
      }
    }
  }
}

// fp32 -> bf16 (RNE), 8 elems/thread/iter, grid-stride (weights only now).
__global__ __launch_bounds__(256) void f32_to_bf16(
    const float* __restrict__ in, unsigned short* __restrict__ out, int n8) {
  int i = blockIdx.x * 256 + threadIdx.x;
  const int stride = gridDim.x * 256;
  for (; i < n8; i += stride) {
    float4 a = ((const float4*)in)[2 * i];
    float4 b = ((const float4*)in)[2 * i + 1];
    unsigned short h[8];
    h[0] = f2bf(a.x); h[1] = f2bf(a.y); h[2] = f2bf(a.z); h[3] = f2bf(a.w);
    h[4] = f2bf(b.x); h[5] = f2bf(b.y); h[6] = f2bf(b.z); h[7] = f2bf(b.w);
    ((uint4*)out)[i] = *(uint4*)h;
  }
}

// In-place softmax over rows of 2048 bf16 scores. One block (256 thr) per row.
__global__ __launch_bounds__(256) void softmax_inplace(unsigned short* __restrict__ S) {
  const size_t row = blockIdx.x;
  unsigned short* p = S + row * 2048;
  const int t = threadIdx.x;
  const int lane = t & 63, wid = t >> 6;

  uint4 x = ((const uint4*)p)[t];
  unsigned short* hs = (unsigned short*)&x;
  float f[8];
#pragma unroll
  for (int j = 0; j < 8; ++j) f[j] = bf2f(hs[j]);

  float mx = f[0];
#pragma unroll
  for (int j = 1; j < 8; ++j) mx = fmaxf(mx, f[j]);
#pragma unroll
  for (int d = 1; d < 64; d <<= 1) mx = fmaxf(mx, __shfl_xor(mx, d));
  __shared__ float redm[4];
  if (lane == 0) redm[wid] = mx;
  __syncthreads();
  mx = fmaxf(fmaxf(redm[0], redm[1]), fmaxf(redm[2], redm[3]));

  float e[8], s = 0.f;
#pragma unroll
  for (int j = 0; j < 8; ++j) {
    e[j] = __expf(f[j] - mx);
    s += e[j];
  }
#pragma unroll
  for (int d = 1; d < 64; d <<= 1) s += __shfl_xor(s, d);
  __shared__ float reds[4];
  if (lane == 0) reds[wid] = s;
  __syncthreads();
  s = reds[0] + reds[1] + reds[2] + reds[3];
  const float inv = 1.f / s;

#pragma unroll
  for (int j = 0; j < 8; ++j) hs[j] = f2bf(e[j] * inv);
  ((uint4*)p)[t] = x;
}

extern "C" void kernel_launch(void* const* d_in, const int* in_sizes, int n_in,
                              void* d_out, int out_size, void* d_ws, size_t ws_size,
                              hipStream_t stream) {
  const float* q_embd = (const float*)d_in[0];
  const float* k_embd = (const float*)d_in[1];
  const float* v_embd = (const float*)d_in[2];
  const float* Wq = (const float*)d_in[3];
  const float* bq = (const float*)d_in[4];
  const float* Wk = (const float*)d_in[5];
  const float* bk = (const float*)d_in[6];
  const float* Wv = (const float*)d_in[7];
  const float* bv = (const float*)d_in[8];

  constexpr int B = 8, QL = 2048, KL = 2048, D = 1024;
  constexpr size_t NE = (size_t)B * QL * D;

  unsigned short* qb = (unsigned short*)d_ws;  // [B*QL][D]
  unsigned short* kb = qb + NE;                // [B*KL][D]
  unsigned short* vT = kb + NE;                // [B][D][KL]
  unsigned short* Sb = vT + NE;                // [B][QL][KL] (64 MiB)
  unsigned short* Wb = Sb;                     // W bf16 staging (dead until QK^T)

  dim3 blk256(256), blk512(512);
  const dim3 gconvW(512);
  // proj grid: gx=D/256=4, gy=(B*QL)/256=64 -> 256 blocks
  const dim3 gproj(4 * 64);

  // --- Q projection (fused fp32->bf16 A-staging) ---
  f32_to_bf16<<<gconvW, blk256, 0, stream>>>(Wq, Wb, D * D / 8);
  gemmP<0><<<gproj, blk512, 0, stream>>>(q_embd, Wb, bq, qb, D, D, 4, 64);
  // --- K projection ---
  f32_to_bf16<<<gconvW, blk256, 0, stream>>>(Wk, Wb, D * D / 8);
  gemmP<0><<<gproj, blk512, 0, stream>>>(k_embd, Wb, bk, kb, D, D, 4, 64);
  // --- V projection (transposed output) ---
  f32_to_bf16<<<gconvW, blk256, 0, stream>>>(Wv, Wb, D * D / 8);
  gemmP<1><<<gproj, blk512, 0, stream>>>(v_embd, Wb, bv, vT, D, D, 4, 64);

  // --- S = (Q @ K^T)/sqrt(D): gx=8, gy=8, gz=8 -> 512 blocks ---
  gemm256<0, false><<<dim3(512), blk512, 0, stream>>>(
      qb, kb, nullptr, 0.03125f, Sb, KL, D, (long)QL * D, (long)KL * D,
      (long)QL * KL, 8, 8);

  // --- P = softmax(S), in place ---
  softmax_inplace<<<dim3(B * QL), blk256, 0, stream>>>(Sb);

  // --- out = P @ V: gx=4, gy=8, gz=8 -> 256 blocks ---
  gemm256<2, false><<<dim3(256), blk512, 0, stream>>>(
      Sb, vT, nullptr, 1.0f, d_out, D, KL, (long)QL * KL, (long)D * KL,
      (long)QL * D, 4, 8);
}

// Round 10
// 368.150 us; speedup vs baseline: 1.5610x; 1.5610x over previous
//
#include <hip/hip_runtime.h>
#include <hip/hip_bf16.h>

typedef float f32x4 __attribute__((ext_vector_type(4)));
typedef float f32x16 __attribute__((ext_vector_type(16)));
typedef __bf16 bf16x8 __attribute__((ext_vector_type(8)));
typedef unsigned short u16x4 __attribute__((ext_vector_type(4)));

__device__ __forceinline__ unsigned short f2bf(float f) {
  unsigned u = __builtin_bit_cast(unsigned, f);
  u += 0x7FFFu + ((u >> 16) & 1u);
  return (unsigned short)(u >> 16);
}
__device__ __forceinline__ float bf2f(unsigned short h) {
  unsigned u = ((unsigned)h) << 16;
  return __builtin_bit_cast(float, u);
}

__device__ __forceinline__ void gload_lds16(const void* g, void* l) {
  __builtin_amdgcn_global_load_lds(
      (const __attribute__((address_space(1))) void*)g,
      (__attribute__((address_space(3))) void*)l, 16, 0, 0);
}

// ------------- 256x256 2-phase-per-K-tile bf16 GEMM (r8 schedule) -----------
// Round-10: MFMA 16x16x32 -> 32x32x16 (m119: 2495 vs 2176 TF peak, half the
// instruction count). Same LDS layout/staging/swizzle/ledger as round 8:
//  ph-A: read all B frags + A-h0 frags; stage A-h1(t+1)->d^1; BAR; 16 MFMA
//        (m-half 0); BAR.
//  ph-B: read A-h1 frags; stage A-h0,B-h0,B-h1(t+2)->d; BAR; 16 MFMA
//        (m-half 1); VMW(6); BAR.
// Frag mapping (32x32x16): A row = lane&31, k = (lane>>5)*8+e; C/D col =
// lane&31, row = (reg&3)+8*(reg>>2)+4*(lane>>5)  [HW-verified m74/m101].
constexpr int BM = 256, BN = 256, BK = 64;

#define BAR() __builtin_amdgcn_s_barrier()
#define VMW(N) asm volatile("s_waitcnt vmcnt(" #N ")" ::: "memory")
#define PRIO(x) __builtin_amdgcn_s_setprio(x)

#define MM32(a_, b_, c_)                                                      \
  c_ = __builtin_amdgcn_mfma_f32_32x32x16_bf16(                               \
      __builtin_bit_cast(bf16x8, a_), __builtin_bit_cast(bf16x8, b_), c_, 0, 0, 0)

template <int OUT_MODE, bool HAS_BIAS>
__global__ __launch_bounds__(512, 2) void gemm256(
    const unsigned short* __restrict__ A, const unsigned short* __restrict__ B,
    const float* __restrict__ bias, float scale, void* __restrict__ Cv,
    int N, int K, long sA, long sB, long sC, int gx, int gy) {
  __shared__ char sm[131072];  // A: [0,64K): dbuf*32K + half*16K; B: +64K same

  const int nwg = gridDim.x;
  int id = blockIdx.x;
  id = (id & 7) * (nwg >> 3) + (id >> 3);  // XCD swizzle (nwg % 8 == 0)
  const int bx = id % gx;
  const int by = (id / gx) % gy;
  const int bz = id / (gx * gy);

  const int t = threadIdx.x;
  const int lane = t & 63;
  const int w = t >> 6;   // 0..7
  const int wm = w >> 2;  // 0..1
  const int wn = w & 3;   // 0..3

  const int rowBase = by * BM;
  const int colBase = bx * BN;
  const unsigned short* Ab = A + sA * bz;
  const unsigned short* Bb = B + sB * bz;
  const int NT = K >> 6;  // K-tiles of 64 (even, >= 2)

  // staging: half-tile = 128 rows x 64 cols; wave w issue j covers rows
  // [(w+8j)*8,+8); lane l -> row +(l>>3), slot l&7; source chunk inverse-swz.
  const int srl = lane >> 3;
  const int schunk = (lane & 7) ^ srl;

#define STAGE_A(tt, h, d)                                                     \
  do {                                                                        \
    int _kt = (tt); if (_kt > NT - 1) _kt = NT - 1;                           \
    const int _k0 = _kt << 6;                                                 \
    _Pragma("unroll") for (int _j = 0; _j < 2; ++_j) {                        \
      const int _r = (w + 8 * _j) * 8 + srl;                                  \
      gload_lds16(Ab + (size_t)(rowBase + (h) * 128 + _r) * K + _k0 + schunk * 8, \
                  sm + (d) * 32768 + (h) * 16384 + (w + 8 * _j) * 1024);      \
    }                                                                         \
  } while (0)
#define STAGE_B(tt, h, d)                                                     \
  do {                                                                        \
    int _kt = (tt); if (_kt > NT - 1) _kt = NT - 1;                           \
    const int _k0 = _kt << 6;                                                 \
    _Pragma("unroll") for (int _j = 0; _j < 2; ++_j) {                        \
      const int _r = (w + 8 * _j) * 8 + srl;                                  \
      gload_lds16(Bb + (size_t)(colBase + (h) * 128 + _r) * K + _k0 + schunk * 8, \
                  sm + 65536 + (d) * 32768 + (h) * 16384 + (w + 8 * _j) * 1024); \
    }                                                                         \
  } while (0)

  // 32x32 fragment reads: A row (local in half) = wm*64 + rt*32 + l31,
  // B col = wn*32 + l31 (half nh selects 16KB region). chunk = ks*2 + hi;
  // byte = row*128 + ((chunk ^ (row&7))<<4); row&7 == l31&7.
  const int l31 = lane & 31;
  const int hi = lane >> 5;
  const int sx = l31 & 7;
  const int aB = (wm * 64 + l31) * 128;
  const int bB = 65536 + (wn * 32 + l31) * 128;

  uint4 Ar[2][4], Br[2][4];
  f32x16 acc[4][2];
#pragma unroll
  for (int mi = 0; mi < 4; ++mi)
#pragma unroll
    for (int ni = 0; ni < 2; ++ni)
#pragma unroll
      for (int e = 0; e < 16; ++e) acc[mi][ni][e] = 0.f;

#define READ_A32(d, mh)                                                       \
  do {                                                                        \
    _Pragma("unroll") for (int rt = 0; rt < 2; ++rt)                          \
      _Pragma("unroll") for (int ks = 0; ks < 4; ++ks)                        \
        Ar[rt][ks] = *(const uint4*)(sm + (d) * 32768 + (mh) * 16384 + aB +   \
                                     rt * 4096 + (((ks * 2 + hi) ^ sx) << 4)); \
  } while (0)
#define READ_B32(d)                                                           \
  do {                                                                        \
    _Pragma("unroll") for (int ni = 0; ni < 2; ++ni)                          \
      _Pragma("unroll") for (int ks = 0; ks < 4; ++ks)                        \
        Br[ni][ks] = *(const uint4*)(sm + (d) * 32768 + bB + ni * 16384 +     \
                                     (((ks * 2 + hi) ^ sx) << 4));            \
  } while (0)

#define MFMA_PH32(mh)                                                         \
  do {                                                                        \
    _Pragma("unroll") for (int ks = 0; ks < 4; ++ks)                          \
      _Pragma("unroll") for (int rt = 0; rt < 2; ++rt)                        \
        _Pragma("unroll") for (int ni = 0; ni < 2; ++ni)                      \
          MM32(Ar[rt][ks], Br[ni][ks], acc[(mh) * 2 + rt][ni]);               \
  } while (0)

  // Two phases per K-tile; stages target regions >=1 barrier past their last
  // read (A-h1 of buf d^1 last read at ph-B of the previous tile; A-h0/B-h0/
  // B-h1 of buf d last read at ph-A of this tile). vmcnt queue at VMW(6):
  // [A-h1(t+1) x2][A0,B0,B1(t+2) x6] -> waits for tile t+1 fully landed.
#define TILE2(t_, d_)                                                         \
  do {                                                                        \
    /* ph-A */ READ_B32(d_); READ_A32(d_, 0);                                 \
    STAGE_A((t_) + 1, 1, (d_) ^ 1);                                           \
    BAR();                                                                    \
    PRIO(1); MFMA_PH32(0); PRIO(0);                                           \
    BAR();                                                                    \
    /* ph-B */ READ_A32(d_, 1);                                               \
    STAGE_A((t_) + 2, 0, d_); STAGE_B((t_) + 2, 0, d_); STAGE_B((t_) + 2, 1, d_); \
    BAR();                                                                    \
    PRIO(1); MFMA_PH32(1); PRIO(0);                                           \
    VMW(6);                                                                   \
    BAR();                                                                    \
  } while (0)

  // prologue: t0 fully staged + t1's A-h0,B-h0,B-h1; A-h1(t1) staged at tile0
  // ph-A. VMW(6) = t0 landed, t1's 6 in flight.
  STAGE_A(0, 0, 0); STAGE_B(0, 0, 0); STAGE_B(0, 1, 0); STAGE_A(0, 1, 0);
  STAGE_A(1, 0, 1); STAGE_B(1, 0, 1); STAGE_B(1, 1, 1);
  VMW(6);
  BAR();

  for (int i = 0; i < (NT >> 1); ++i) {
    TILE2(2 * i, 0);
    TILE2(2 * i + 1, 1);
  }
  VMW(0);  // drain clamped tail prefetches before teardown

  // Epilogue (32x32 C/D): col = colBase + ni*128 + wn*32 + l31;
  // row = rowBase + (mi>>1)*128 + wm*64 + (mi&1)*32 + 4*hi + 8*rg + j.
#pragma unroll
  for (int ni = 0; ni < 2; ++ni) {
    const int col = colBase + ni * 128 + wn * 32 + l31;
    float bvv = 0.f;
    if constexpr (HAS_BIAS) bvv = bias[col];
#pragma unroll
    for (int mi = 0; mi < 4; ++mi) {
      const int row00 = rowBase + (mi >> 1) * 128 + wm * 64 + (mi & 1) * 32 + hi * 4;
#pragma unroll
      for (int rg = 0; rg < 4; ++rg) {
        const int r0 = row00 + rg * 8;
        if constexpr (OUT_MODE == 0) {
          unsigned short* C = (unsigned short*)Cv + sC * bz;
#pragma unroll
          for (int j = 0; j < 4; ++j)
            C[(size_t)(r0 + j) * N + col] =
                f2bf(acc[mi][ni][rg * 4 + j] * scale + bvv);
        } else if constexpr (OUT_MODE == 1) {
          unsigned short* C = (unsigned short*)Cv;
          const int b = r0 >> 11, s = r0 & 2047;
          u16x4 pk;
#pragma unroll
          for (int j = 0; j < 4; ++j)
            pk[j] = f2bf(acc[mi][ni][rg * 4 + j] * scale + bvv);
          *(u16x4*)&C[((size_t)b * N + col) * 2048 + s] = pk;
        } else {
          float* C = (float*)Cv + sC * bz;
#pragma unroll
          for (int j = 0; j < 4; ++j)
            C[(size_t)(r0 + j) * N + col] = acc[mi][ni][rg * 4 + j] * scale + bvv;
        }
      }
    }
  }
}

// fp32 -> bf16 (RNE) for one embedding (ne8 x 8 elems) and one weight
// (nw8 x 8 elems) in a single launch; grid-stride over both.
__global__ __launch_bounds__(256) void conv_pair(
    const float* __restrict__ e, const float* __restrict__ wt,
    unsigned short* __restrict__ eo, unsigned short* __restrict__ wo,
    int ne8, int nw8) {
  const int tot = ne8 + nw8;
  const int stride = gridDim.x * 256;
  for (int i = blockIdx.x * 256 + threadIdx.x; i < tot; i += stride) {
    const float* src;
    unsigned short* dst;
    int k;
    if (i < ne8) { src = e; dst = eo; k = i; }
    else { src = wt; dst = wo; k = i - ne8; }
    float4 a = ((const float4*)src)[2 * k];
    float4 b = ((const float4*)src)[2 * k + 1];
    unsigned short h[8];
    h[0] = f2bf(a.x); h[1] = f2bf(a.y); h[2] = f2bf(a.z); h[3] = f2bf(a.w);
    h[4] = f2bf(b.x); h[5] = f2bf(b.y); h[6] = f2bf(b.z); h[7] = f2bf(b.w);
    ((uint4*)dst)[k] = *(uint4*)h;
  }
}

// In-place softmax over rows of 2048 bf16 scores. One block (256 thr) per row.
__global__ __launch_bounds__(256) void softmax_inplace(unsigned short* __restrict__ S) {
  const size_t row = blockIdx.x;
  unsigned short* p = S + row * 2048;
  const int t = threadIdx.x;
  const int lane = t & 63, wid = t >> 6;

  uint4 x = ((const uint4*)p)[t];
  unsigned short* hs = (unsigned short*)&x;
  float f[8];
#pragma unroll
  for (int j = 0; j < 8; ++j) f[j] = bf2f(hs[j]);

  float mx = f[0];
#pragma unroll
  for (int j = 1; j < 8; ++j) mx = fmaxf(mx, f[j]);
#pragma unroll
  for (int d = 1; d < 64; d <<= 1) mx = fmaxf(mx, __shfl_xor(mx, d));
  __shared__ float redm[4];
  if (lane == 0) redm[wid] = mx;
  __syncthreads();
  mx = fmaxf(fmaxf(redm[0], redm[1]), fmaxf(redm[2], redm[3]));

  float e[8], s = 0.f;
#pragma unroll
  for (int j = 0; j < 8; ++j) {
    e[j] = __expf(f[j] - mx);
    s += e[j];
  }
#pragma unroll
  for (int d = 1; d < 64; d <<= 1) s += __shfl_xor(s, d);
  __shared__ float reds[4];
  if (lane == 0) reds[wid] = s;
  __syncthreads();
  s = reds[0] + reds[1] + reds[2] + reds[3];
  const float inv = 1.f / s;

#pragma unroll
  for (int j = 0; j < 8; ++j) hs[j] = f2bf(e[j] * inv);
  ((uint4*)p)[t] = x;
}

extern "C" void kernel_launch(void* const* d_in, const int* in_sizes, int n_in,
                              void* d_out, int out_size, void* d_ws, size_t ws_size,
                              hipStream_t stream) {
  const float* q_embd = (const float*)d_in[0];
  const float* k_embd = (const float*)d_in[1];
  const float* v_embd = (const float*)d_in[2];
  const float* Wq = (const float*)d_in[3];
  const float* bq = (const float*)d_in[4];
  const float* Wk = (const float*)d_in[5];
  const float* bk = (const float*)d_in[6];
  const float* Wv = (const float*)d_in[7];
  const float* bv = (const float*)d_in[8];

  constexpr int B = 8, QL = 2048, KL = 2048, D = 1024;
  constexpr size_t NE = (size_t)B * QL * D;

  unsigned short* qb = (unsigned short*)d_ws;  // [B*QL][D]
  unsigned short* kb = qb + NE;                // [B*KL][D]
  unsigned short* vT = kb + NE;                // [B][D][KL]
  unsigned short* Sb = vT + NE;                // [B][QL][KL] (64 MiB)
  unsigned short* Xe = Sb;                     // conv staging (dead until QK^T)
  unsigned short* Wb = Sb + NE;

  dim3 blk256(256), blk512(512);
  const dim3 gconv(2048);
  // proj grid: gx=D/256=4, gy=(B*QL)/256=64 -> 256 blocks
  const dim3 gproj(4 * 64);
  constexpr int NE8 = (int)(NE / 8), NW8 = D * D / 8;

  // --- Q projection ---
  conv_pair<<<gconv, blk256, 0, stream>>>(q_embd, Wq, Xe, Wb, NE8, NW8);
  gemm256<0, true><<<gproj, blk512, 0, stream>>>(Xe, Wb, bq, 1.0f, qb, D, D,
                                                 0L, 0L, 0L, 4, 64);
  // --- K projection ---
  conv_pair<<<gconv, blk256, 0, stream>>>(k_embd, Wk, Xe, Wb, NE8, NW8);
  gemm256<0, true><<<gproj, blk512, 0, stream>>>(Xe, Wb, bk, 1.0f, kb, D, D,
                                                 0L, 0L, 0L, 4, 64);
  // --- V projection (transposed output) ---
  conv_pair<<<gconv, blk256, 0, stream>>>(v_embd, Wv, Xe, Wb, NE8, NW8);
  gemm256<1, true><<<gproj, blk512, 0, stream>>>(Xe, Wb, bv, 1.0f, vT, D, D,
                                                 0L, 0L, 0L, 4, 64);

  // --- S = (Q @ K^T)/sqrt(D): gx=8, gy=8, gz=8 -> 512 blocks ---
  gemm256<0, false><<<dim3(512), blk512, 0, stream>>>(
      qb, kb, nullptr, 0.03125f, Sb, KL, D, (long)QL * D, (long)KL * D,
      (long)QL * KL, 8, 8);

  // --- P = softmax(S), in place ---
  softmax_inplace<<<dim3(B * QL), blk256, 0, stream>>>(Sb);

  // --- out = P @ V: gx=4, gy=8, gz=8 -> 256 blocks ---
  gemm256<2, false><<<dim3(256), blk512, 0, stream>>>(
      Sb, vT, nullptr, 1.0f, d_out, D, KL, (long)QL * KL, (long)D * KL,
      (long)QL * D, 4, 8);
}